// Round 11
// baseline (47.764 us; speedup 1.0000x reference)
//
#include <hip/hip_runtime.h>

#define CC 8
#define HW 4096
#define L2E 1.4426950408889634f

typedef __attribute__((ext_vector_type(4))) float f32x4;

// Full-wave (64-lane) sum reduction on the VALU pipe via DPP (lands in lane 63).
static __device__ __forceinline__ float dpp_sum64(float v) {
#define DPPSTEP(CTRL, RM, BM)                                              \
  v += __int_as_float(__builtin_amdgcn_update_dpp(                         \
      0, __float_as_int(v), CTRL, RM, BM, true));
  DPPSTEP(0x111, 0xf, 0xf)   // row_shr:1
  DPPSTEP(0x112, 0xf, 0xf)   // row_shr:2
  DPPSTEP(0x114, 0xf, 0xe)   // row_shr:4
  DPPSTEP(0x118, 0xf, 0xc)   // row_shr:8
  DPPSTEP(0x142, 0xa, 0xf)   // row_bcast:15
  DPPSTEP(0x143, 0xc, 0xf)   // row_bcast:31
#undef DPPSTEP
  return v;
}

// Single node: 256 blocks (4 batches x 64-pixel tiles) x 1024 threads (16 waves,
// 4 waves/SIMD -- R10 showed 2 waves/SIMD leaves the exp/VALU chains
// latency-exposed; this doubles TLP at identical total work).
//   P0a: kv for 4 m's/thread -> 32 KB LDS (broadcast-read in P2)
//   P0b: Gram/rowsum partials from the same registers, DPP-reduced (VALU pipe)
//   P0c: pq + xn for this lane's pixel
//   P2 : PAM rank-1 softmax; wave w scans m in [w*256, w*256+256) via
//        wave-uniform ds_read_b128 broadcasts (DS pipe, overlaps VALU/trans)
//   P3 : wave 0 combines + CAM 8x8 softmax;  P4: epilogue (waves 0-7)
__global__ __launch_bounds__(1024) void kFused(
    const float* __restrict__ x,
    const float* __restrict__ cwq, const float* __restrict__ cbq,
    const float* __restrict__ cwk, const float* __restrict__ cbk,
    const float* __restrict__ cwv, const float* __restrict__ cbv,
    const float* __restrict__ pwq, const float* __restrict__ pbq,
    const float* __restrict__ pwk, const float* __restrict__ pbk,
    const float* __restrict__ pwv, const float* __restrict__ pbv,
    float* __restrict__ out)
{
  const int b = blockIdx.x >> 6, tile = blockIdx.x & 63;
  const int n0 = tile * 64;
  const int t = threadIdx.x, ln = t & 63;
  const int wid = __builtin_amdgcn_readfirstlane(t >> 6);   // wave 0..15

  __shared__ __align__(16) float kv[HW * 2];                // 32 KB {k2,v} pairs
  __shared__ float redd[16][64], redn[16][64];              // 8 KB
  __shared__ float gpart[16][44];                           // 2.75 KB
  __shared__ float sums[44], Gl[64], Ll[64], Al[64], Mp[64], cvs[8], outp[64];

  const float* xb = x + b * CC * HW;

  // ---- P0a: kv for my 4 m's (m = 4t..4t+3) ----
  f32x4 xa[CC];
  {
    const int m4 = t * 4;
    #pragma unroll
    for (int c = 0; c < CC; ++c)
      xa[c] = *(const f32x4*)(xb + c * HW + m4);
    f32x4 o0, o1;
    #pragma unroll
    for (int j = 0; j < 4; ++j) {
      float kk = pbk[0], vv = pbv[0];
      #pragma unroll
      for (int c = 0; c < CC; ++c) {
        kk = fmaf(pwk[c], xa[c][j], kk);
        vv = fmaf(pwv[c], xa[c][j], vv);
      }
      kk *= L2E;
      if (j == 0)      { o0[0] = kk; o0[1] = vv; }
      else if (j == 1) { o0[2] = kk; o0[3] = vv; }
      else if (j == 2) { o1[0] = kk; o1[1] = vv; }
      else             { o1[2] = kk; o1[3] = vv; }
    }
    f32x4* kv4 = (f32x4*)kv;
    kv4[t * 2 + 0] = o0;
    kv4[t * 2 + 1] = o1;
  }

  // ---- P0b: Gram + rowsum partials from the already-loaded registers ----
  {
    float acc[44];
    #pragma unroll
    for (int i = 0; i < 44; ++i) acc[i] = 0.f;
    #pragma unroll
    for (int j = 0; j < 4; ++j) {
      float xv[CC];
      #pragma unroll
      for (int c = 0; c < CC; ++c) xv[c] = xa[c][j];
      int k = 0;
      #pragma unroll
      for (int c = 0; c < CC; ++c) {
        #pragma unroll
        for (int d = c; d < CC; ++d) { acc[k] = fmaf(xv[c], xv[d], acc[k]); ++k; }
      }
      #pragma unroll
      for (int c = 0; c < CC; ++c) acc[36 + c] += xv[c];
    }
    #pragma unroll
    for (int i = 0; i < 44; ++i) acc[i] = dpp_sum64(acc[i]);
    if (ln == 63) {
      #pragma unroll
      for (int i = 0; i < 44; ++i) gpart[wid][i] = acc[i];   // static idx
    }
  }

  // ---- P0c: pq + xn for pixel n0+ln ----
  float xn[CC];
  #pragma unroll
  for (int c = 0; c < CC; ++c) xn[c] = xb[c * HW + n0 + ln];
  float a = pbq[0];
  #pragma unroll
  for (int c = 0; c < CC; ++c) a = fmaf(pwq[c], xn[c], a);

  __syncthreads();

  // ---- P2: PAM direct; wave wid covers m in [wid*256, wid*256+256) ----
  {
    const f32x4* kvw = ((const f32x4*)kv) + (wid << 7);     // 128 f32x4 = 256 m
    float dA = 0, dB = 0, dC = 0, dD = 0;
    float nA = 0, nB = 0, nC = 0, nD = 0;
    #pragma unroll 2
    for (int i = 0; i < 128; i += 4) {
      const f32x4 p0 = kvw[i], p1 = kvw[i + 1], p2 = kvw[i + 2], p3 = kvw[i + 3];
      float e;
      e = __builtin_amdgcn_exp2f(a * p0[0]); dA += e; nA = fmaf(e, p0[1], nA);
      e = __builtin_amdgcn_exp2f(a * p0[2]); dA += e; nA = fmaf(e, p0[3], nA);
      e = __builtin_amdgcn_exp2f(a * p1[0]); dB += e; nB = fmaf(e, p1[1], nB);
      e = __builtin_amdgcn_exp2f(a * p1[2]); dB += e; nB = fmaf(e, p1[3], nB);
      e = __builtin_amdgcn_exp2f(a * p2[0]); dC += e; nC = fmaf(e, p2[1], nC);
      e = __builtin_amdgcn_exp2f(a * p2[2]); dC += e; nC = fmaf(e, p2[3], nC);
      e = __builtin_amdgcn_exp2f(a * p3[0]); dD += e; nD = fmaf(e, p3[1], nD);
      e = __builtin_amdgcn_exp2f(a * p3[2]); dD += e; nD = fmaf(e, p3[3], nD);
    }
    redd[wid][ln] = (dA + dB) + (dC + dD);
    redn[wid][ln] = (nA + nB) + (nC + nD);
  }
  __syncthreads();

  // ---- P3: wave 0: PAM combine + Gram total + CAM 8x8 softmax ----
  if (t < 64) {
    float D = 0.f, N = 0.f;
    #pragma unroll
    for (int s = 0; s < 16; ++s) { D += redd[s][t]; N += redn[s][t]; }
    outp[t] = N / D;
  }
  if (t < 44) {
    float s = 0.f;
    #pragma unroll
    for (int w = 0; w < 16; ++w) s += gpart[w][t];
    sums[t] = s;
  }
  __syncthreads();

  const int c = ln >> 3, d = ln & 7;
  if (t < 64) {
    const int lo = min(c, d), hi = max(c, d);
    Gl[t] = sums[lo * 8 + hi - lo * (lo + 1) / 2];
  }
  __syncthreads();

  float Lv = 0.f;
  if (t < 64) {
    float qs = 0.f, ks = 0.f;
    #pragma unroll
    for (int e = 0; e < 8; ++e) {
      qs = fmaf(cwq[c * 8 + e], sums[36 + e], qs);
      ks = fmaf(cwk[d * 8 + e], sums[36 + e], ks);
    }
    float A = 0.f;
    #pragma unroll
    for (int e = 0; e < 8; ++e) {
      float inner = 0.f;
      #pragma unroll
      for (int f = 0; f < 8; ++f) inner = fmaf(Gl[e * 8 + f], cwk[d * 8 + f], inner);
      A = fmaf(cwq[c * 8 + e], inner, A);
    }
    Lv = A + qs * cbk[d] + cbq[c] * ks + 4096.f * cbq[c] * cbk[d];
    Ll[t] = Lv;
  }
  __syncthreads();

  if (t < 64) {
    float mx = -INFINITY;
    #pragma unroll
    for (int f = 0; f < 8; ++f) mx = fmaxf(mx, Ll[c * 8 + f]);
    float ssum = 0.f;
    #pragma unroll
    for (int f = 0; f < 8; ++f) ssum += __expf(Ll[c * 8 + f] - mx);
    Al[t] = __expf(Lv - mx) / ssum;
  }
  __syncthreads();

  if (t < 64) {
    float M = 0.f;
    #pragma unroll
    for (int f = 0; f < 8; ++f) M = fmaf(Al[c * 8 + f], cwv[f * 8 + d], M);
    if (d == c) M += 2.f;            // +2I: residual x appears in both CAM and PAM
    Mp[t] = M;
    if (d == 0) {
      float cvv = 0.f;
      #pragma unroll
      for (int f = 0; f < 8; ++f) cvv = fmaf(Al[c * 8 + f], cbv[f], cvv);
      cvs[c] = cvv;
    }
  }
  __syncthreads();

  // ---- P4: epilogue, waves 0-7: thread (wid, ln) -> channel wid, pixel n0+ln ----
  if (t < 512) {
    float o = cvs[wid] + outp[ln];
    #pragma unroll
    for (int dd = 0; dd < 8; ++dd) o = fmaf(Mp[wid * 8 + dd], xn[dd], o);
    out[(b * 8 + wid) * HW + n0 + ln] = o;
  }
}

extern "C" void kernel_launch(void* const* d_in, const int* in_sizes, int n_in,
                              void* d_out, int out_size, void* d_ws, size_t ws_size,
                              hipStream_t stream) {
  const float* x   = (const float*)d_in[0];
  const float* cwq = (const float*)d_in[1];
  const float* cbq = (const float*)d_in[2];
  const float* cwk = (const float*)d_in[3];
  const float* cbk = (const float*)d_in[4];
  const float* cwv = (const float*)d_in[5];
  const float* cbv = (const float*)d_in[6];
  const float* pwq = (const float*)d_in[7];
  const float* pbq = (const float*)d_in[8];
  const float* pwk = (const float*)d_in[9];
  const float* pbk = (const float*)d_in[10];
  const float* pwv = (const float*)d_in[11];
  const float* pbv = (const float*)d_in[12];
  float* out = (float*)d_out;

  hipLaunchKernelGGL(kFused, dim3(256), dim3(1024), 0, stream,
                     x, cwq, cbq, cwk, cbk, cwv, cbv,
                     pwq, pbq, pwk, pbk, pwv, pbv, out);
}

// Round 12
// 20.627 us; speedup vs baseline: 2.3156x; 2.3156x over previous
//
#include <hip/hip_runtime.h>

#define CC 8
#define HW 4096
#define L2E 1.4426950408889634f

typedef __attribute__((ext_vector_type(4))) float f32x4;
typedef __attribute__((ext_vector_type(2))) float f32x2;

// Full-wave (64-lane) sum reduction on the VALU pipe via DPP (lands in lane 63).
static __device__ __forceinline__ float dpp_sum64(float v) {
#define DPPSTEP(CTRL, RM, BM)                                              \
  v += __int_as_float(__builtin_amdgcn_update_dpp(                         \
      0, __float_as_int(v), CTRL, RM, BM, true));
  DPPSTEP(0x111, 0xf, 0xf)   // row_shr:1
  DPPSTEP(0x112, 0xf, 0xf)   // row_shr:2
  DPPSTEP(0x114, 0xf, 0xe)   // row_shr:4
  DPPSTEP(0x118, 0xf, 0xc)   // row_shr:8
  DPPSTEP(0x142, 0xa, 0xf)   // row_bcast:15
  DPPSTEP(0x143, 0xc, 0xf)   // row_bcast:31
#undef DPPSTEP
  return v;
}

// Packed 2-m PAM step: v_pk_mul (arg) + 2x v_exp + v_pk_add (den) + v_pk_fma (num).
static __device__ __forceinline__ void step2(f32x2 kk, f32x2 vv, f32x2 aa,
                                             f32x2& dd, f32x2& nn) {
  f32x2 arg = aa * kk;                       // v_pk_mul_f32
  f32x2 ee;
  ee[0] = __builtin_amdgcn_exp2f(arg[0]);
  ee[1] = __builtin_amdgcn_exp2f(arg[1]);
  dd += ee;                                  // v_pk_add_f32
  nn = __builtin_elementwise_fma(ee, vv, nn); // v_pk_fma_f32
}

// Single node: 256 blocks (4 batches x 64-pixel tiles) x 512 threads (8 waves).
// R9 structure (best, 21.6us) with two P2 instruction-count cuts:
//   - k2 and pv in SEPARATE LDS arrays -> 1 ds_read_b128 = 4 m's (0.5 DS/m)
//   - f32x2 packed VALU (pk_mul/pk_add/pk_fma) -> 1.5 VALU/m
// 1024-thr variants spill (R5: VGPR64, R11: VGPR52 -> 20-80MB scratch); stay 512.
__global__ __launch_bounds__(512) void kFused(
    const float* __restrict__ x,
    const float* __restrict__ cwq, const float* __restrict__ cbq,
    const float* __restrict__ cwk, const float* __restrict__ cbk,
    const float* __restrict__ cwv, const float* __restrict__ cbv,
    const float* __restrict__ pwq, const float* __restrict__ pbq,
    const float* __restrict__ pwk, const float* __restrict__ pbk,
    const float* __restrict__ pwv, const float* __restrict__ pbv,
    float* __restrict__ out)
{
  const int b = blockIdx.x >> 6, tile = blockIdx.x & 63;
  const int n0 = tile * 64;
  const int t = threadIdx.x, ln = t & 63;
  const int wid = __builtin_amdgcn_readfirstlane(t >> 6);   // wave 0..7

  __shared__ __align__(16) float k2s[HW];                   // 16 KB: pk*log2e
  __shared__ __align__(16) float pvs[HW];                   // 16 KB: pv
  __shared__ float redd[8][64], redn[8][64];                // 4 KB
  __shared__ float gpart[8][44];
  __shared__ float sums[44], Gl[64], Ll[64], Al[64], Mp[64], cvs[8], outp[64];

  const float* xb = x + b * CC * HW;

  // ---- P0a: k2/pv for my 8 m's (m = 8t..8t+7) ----
  f32x4 xa[CC], xc[CC];
  {
    const int m8 = t * 8;
    #pragma unroll
    for (int c = 0; c < CC; ++c) {
      xa[c] = *(const f32x4*)(xb + c * HW + m8);
      xc[c] = *(const f32x4*)(xb + c * HW + m8 + 4);
    }
    f32x4 ka, kb, va, vb;
    #pragma unroll
    for (int j = 0; j < 8; ++j) {
      float kk = pbk[0], vv = pbv[0];
      #pragma unroll
      for (int c = 0; c < CC; ++c) {
        const float xv = (j < 4) ? xa[c][j & 3] : xc[c][j & 3];
        kk = fmaf(pwk[c], xv, kk);
        vv = fmaf(pwv[c], xv, vv);
      }
      kk *= L2E;
      if (j < 4) { ka[j] = kk; va[j] = vv; }
      else       { kb[j & 3] = kk; vb[j & 3] = vv; }
    }
    ((f32x4*)k2s)[t * 2 + 0] = ka;
    ((f32x4*)k2s)[t * 2 + 1] = kb;
    ((f32x4*)pvs)[t * 2 + 0] = va;
    ((f32x4*)pvs)[t * 2 + 1] = vb;
  }

  // ---- P0b: Gram + rowsum partials from the already-loaded registers ----
  {
    float acc[44];
    #pragma unroll
    for (int i = 0; i < 44; ++i) acc[i] = 0.f;
    #pragma unroll
    for (int j = 0; j < 8; ++j) {
      float xv[CC];
      #pragma unroll
      for (int c = 0; c < CC; ++c) xv[c] = (j < 4) ? xa[c][j & 3] : xc[c][j & 3];
      int k = 0;
      #pragma unroll
      for (int c = 0; c < CC; ++c) {
        #pragma unroll
        for (int d = c; d < CC; ++d) { acc[k] = fmaf(xv[c], xv[d], acc[k]); ++k; }
      }
      #pragma unroll
      for (int c = 0; c < CC; ++c) acc[36 + c] += xv[c];
    }
    #pragma unroll
    for (int i = 0; i < 44; ++i) acc[i] = dpp_sum64(acc[i]);
    if (ln == 63) {
      #pragma unroll
      for (int i = 0; i < 44; ++i) gpart[wid][i] = acc[i];   // static idx
    }
  }

  // ---- P0c: pq + xn for pixel n0+ln ----
  float xn[CC];
  #pragma unroll
  for (int c = 0; c < CC; ++c) xn[c] = xb[c * HW + n0 + ln];
  float a = pbq[0];
  #pragma unroll
  for (int c = 0; c < CC; ++c) a = fmaf(pwq[c], xn[c], a);

  __syncthreads();

  // ---- P2: PAM direct; wave wid covers m in [wid*512, wid*512+512) ----
  {
    const f32x4* kp = ((const f32x4*)k2s) + (wid << 7);   // 128 f32x4 = 512 m
    const f32x4* vp = ((const f32x4*)pvs) + (wid << 7);
    f32x2 aa; aa[0] = a; aa[1] = a;
    f32x2 z; z[0] = 0.f; z[1] = 0.f;
    f32x2 dA = z, dB = z, dC = z, dD = z;
    f32x2 nA = z, nB = z, nC = z, nD = z;
    #pragma unroll 2
    for (int i = 0; i < 128; i += 2) {                    // 8 m per iter
      const f32x4 k4a = kp[i], k4b = kp[i + 1];
      const f32x4 v4a = vp[i], v4b = vp[i + 1];
      f32x2 kk, vv;
      kk[0] = k4a[0]; kk[1] = k4a[1]; vv[0] = v4a[0]; vv[1] = v4a[1];
      step2(kk, vv, aa, dA, nA);
      kk[0] = k4a[2]; kk[1] = k4a[3]; vv[0] = v4a[2]; vv[1] = v4a[3];
      step2(kk, vv, aa, dB, nB);
      kk[0] = k4b[0]; kk[1] = k4b[1]; vv[0] = v4b[0]; vv[1] = v4b[1];
      step2(kk, vv, aa, dC, nC);
      kk[0] = k4b[2]; kk[1] = k4b[3]; vv[0] = v4b[2]; vv[1] = v4b[3];
      step2(kk, vv, aa, dD, nD);
    }
    const f32x2 dS = (dA + dB) + (dC + dD);
    const f32x2 nS = (nA + nB) + (nC + nD);
    redd[wid][ln] = dS[0] + dS[1];
    redn[wid][ln] = nS[0] + nS[1];
  }
  __syncthreads();

  // ---- P3: wave 0: PAM combine + Gram total + CAM 8x8 softmax ----
  if (t < 64) {
    float D = 0.f, N = 0.f;
    #pragma unroll
    for (int s = 0; s < 8; ++s) { D += redd[s][t]; N += redn[s][t]; }
    outp[t] = N / D;
  }
  if (t < 44) {
    float s = 0.f;
    #pragma unroll
    for (int w = 0; w < 8; ++w) s += gpart[w][t];
    sums[t] = s;
  }
  __syncthreads();

  const int c = ln >> 3, d = ln & 7;
  if (t < 64) {
    const int lo = min(c, d), hi = max(c, d);
    Gl[t] = sums[lo * 8 + hi - lo * (lo + 1) / 2];
  }
  __syncthreads();

  float Lv = 0.f;
  if (t < 64) {
    float qs = 0.f, ks = 0.f;
    #pragma unroll
    for (int e = 0; e < 8; ++e) {
      qs = fmaf(cwq[c * 8 + e], sums[36 + e], qs);
      ks = fmaf(cwk[d * 8 + e], sums[36 + e], ks);
    }
    float A = 0.f;
    #pragma unroll
    for (int e = 0; e < 8; ++e) {
      float inner = 0.f;
      #pragma unroll
      for (int f = 0; f < 8; ++f) inner = fmaf(Gl[e * 8 + f], cwk[d * 8 + f], inner);
      A = fmaf(cwq[c * 8 + e], inner, A);
    }
    Lv = A + qs * cbk[d] + cbq[c] * ks + 4096.f * cbq[c] * cbk[d];
    Ll[t] = Lv;
  }
  __syncthreads();

  if (t < 64) {
    float mx = -INFINITY;
    #pragma unroll
    for (int f = 0; f < 8; ++f) mx = fmaxf(mx, Ll[c * 8 + f]);
    float ssum = 0.f;
    #pragma unroll
    for (int f = 0; f < 8; ++f) ssum += __expf(Ll[c * 8 + f] - mx);
    Al[t] = __expf(Lv - mx) / ssum;
  }
  __syncthreads();

  if (t < 64) {
    float M = 0.f;
    #pragma unroll
    for (int f = 0; f < 8; ++f) M = fmaf(Al[c * 8 + f], cwv[f * 8 + d], M);
    if (d == c) M += 2.f;            // +2I: residual x appears in both CAM and PAM
    Mp[t] = M;
    if (d == 0) {
      float cvv = 0.f;
      #pragma unroll
      for (int f = 0; f < 8; ++f) cvv = fmaf(Al[c * 8 + f], cbv[f], cvv);
      cvs[c] = cvv;
    }
  }
  __syncthreads();

  // ---- P4: epilogue, thread (wid, ln) -> channel wid, pixel n0+ln ----
  {
    float o = cvs[wid] + outp[ln];
    #pragma unroll
    for (int dd = 0; dd < 8; ++dd) o = fmaf(Mp[wid * 8 + dd], xn[dd], o);
    out[(b * 8 + wid) * HW + n0 + ln] = o;
  }
}

extern "C" void kernel_launch(void* const* d_in, const int* in_sizes, int n_in,
                              void* d_out, int out_size, void* d_ws, size_t ws_size,
                              hipStream_t stream) {
  const float* x   = (const float*)d_in[0];
  const float* cwq = (const float*)d_in[1];
  const float* cbq = (const float*)d_in[2];
  const float* cwk = (const float*)d_in[3];
  const float* cbk = (const float*)d_in[4];
  const float* cwv = (const float*)d_in[5];
  const float* cbv = (const float*)d_in[6];
  const float* pwq = (const float*)d_in[7];
  const float* pbq = (const float*)d_in[8];
  const float* pwk = (const float*)d_in[9];
  const float* pbk = (const float*)d_in[10];
  const float* pwv = (const float*)d_in[11];
  const float* pbv = (const float*)d_in[12];
  float* out = (float*)d_out;

  hipLaunchKernelGGL(kFused, dim3(256), dim3(512), 0, stream,
                     x, cwq, cbq, cwk, cbk, cwv, cbv,
                     pwq, pbq, pwk, pbk, pwv, pbv, out);
}